// Round 1
// baseline (332.549 us; speedup 1.0000x reference)
//
#include <hip/hip_runtime.h>
#include <hip/hip_bf16.h>

// MahalanobisDistanceLayer: B=8192, D=64.
// q = E @ E^T with E = (a-b) * rsqrt(var_per_feature(concat(a,b)+eps));
// out[i] = sum_j (q<0 ? 0 : sqrt(q)) + B*EPS_OUT, for (anchor,positive) and (anchor,negative).

#define BROWS 8192
#define DFEAT 64
#define NCO   16384          // 2*BROWS
#define EPS_IN  1e-4f
#define EPS_OUT 1e-6f

// ---- workspace layout (floats) ----
// [0, 384)    : stats  (6 groups x 64: Sa, Qa, Sp, Qp, Sn, Qn)
// [384, 512)  : inv_std (pair0: [384,448), pair1: [448,512))
// [512, 512 + 2*64*8192) : ET0 then ET1, each [64][8192] k-major
#define WS_STATS   0
#define WS_INVSTD  384
#define WS_ET      512
#define ET_ELEMS   (64 * 8192)

// ---------------------------------------------------------------------------
// Kernel A: per-feature sums and sums-of-squares for all three inputs.
// 128 blocks x 256 threads; each block covers 64 rows.
__global__ __launch_bounds__(256) void stats_kernel(
    const float* __restrict__ a, const float* __restrict__ p,
    const float* __restrict__ n, float* __restrict__ stats) {
  __shared__ float acc[6][64];
  int tid = threadIdx.x;
  if (tid < 64) {
    #pragma unroll
    for (int g = 0; g < 6; ++g) acc[g][tid] = 0.f;
  }
  __syncthreads();
  int d  = tid & 63;
  int rg = tid >> 6;                 // 0..3
  int row0 = blockIdx.x * 64;
  float sa = 0.f, qa = 0.f, sp = 0.f, qp = 0.f, sn = 0.f, qn = 0.f;
  for (int r = rg; r < 64; r += 4) {
    int idx = (row0 + r) * DFEAT + d;
    float va = a[idx] + EPS_IN; sa += va; qa += va * va;
    float vp = p[idx] + EPS_IN; sp += vp; qp += vp * vp;
    float vn = n[idx] + EPS_IN; sn += vn; qn += vn * vn;
  }
  atomicAdd(&acc[0][d], sa); atomicAdd(&acc[1][d], qa);
  atomicAdd(&acc[2][d], sp); atomicAdd(&acc[3][d], qp);
  atomicAdd(&acc[4][d], sn); atomicAdd(&acc[5][d], qn);
  __syncthreads();
  for (int v = tid; v < 384; v += 256)
    atomicAdd(&stats[v], acc[v >> 6][v & 63]);
}

// ---------------------------------------------------------------------------
// Kernel A2: inv_std[pair][d] = 1/sqrt(var). 1 block x 64 threads.
__global__ void invstd_kernel(const float* __restrict__ stats,
                              float* __restrict__ inv_std) {
  int d = threadIdx.x;
  float sa = stats[0 * 64 + d], qa = stats[1 * 64 + d];
  float sp = stats[2 * 64 + d], qp = stats[3 * 64 + d];
  float sn = stats[4 * 64 + d], qn = stats[5 * 64 + d];
  const float invN = 1.0f / (float)NCO;
  float m1 = (sa + sp) * invN;
  float v1 = (qa + qp) * invN - m1 * m1;
  float m2 = (sa + sn) * invN;
  float v2 = (qa + qn) * invN - m2 * m2;
  inv_std[d]      = 1.0f / sqrtf(v1);
  inv_std[64 + d] = 1.0f / sqrtf(v2);
}

// ---------------------------------------------------------------------------
// Kernel B: ET[pair][d][i] = (a[i][d] - b[i][d]) * inv_std[pair][d]
// LDS-transposed so both reads and writes are coalesced.
// Grid: 256 blocks (pair = bid>>7, tile = bid&127), 256 threads.
__global__ __launch_bounds__(256) void diff_kernel(
    const float* __restrict__ a, const float* __restrict__ p,
    const float* __restrict__ n, const float* __restrict__ inv_std,
    float* __restrict__ ET) {
  __shared__ float tile[64][65];
  int pair = blockIdx.x >> 7;
  int tb   = blockIdx.x & 127;
  int i0   = tb * 64;
  const float* bptr = pair ? n : p;
  const float* istd = inv_std + pair * 64;
  float* et = ET + (size_t)pair * ET_ELEMS;
  int d  = threadIdx.x & 63;
  int rg = threadIdx.x >> 6;
  float is = istd[d];
  for (int r = rg; r < 64; r += 4) {
    int idx = (i0 + r) * DFEAT + d;
    tile[r][d] = (a[idx] - bptr[idx]) * is;
  }
  __syncthreads();
  // write ET[dd][i0 + d] = tile[d][dd]; read stride 65 -> conflict-free
  for (int dd = rg; dd < 64; dd += 4)
    et[(size_t)dd * BROWS + i0 + d] = tile[d][dd];
}

// ---------------------------------------------------------------------------
// Kernel C: out[pair][i] += sum_{j in chunk} f(dot(e_i, e_j)) + chunk*EPS_OUT
// 128x64 tile per block, 8x4 micro-tile, K=64 fully resident in LDS.
// Grid: 2 pairs x 64 i-blocks x 4 j-splits = 512 blocks, 256 threads.
#define BM 128
#define BN 64
#define NSPLIT 4
#define JCHUNK (BROWS / NSPLIT)   // 2048

__global__ __launch_bounds__(256) void mdist_kernel(
    const float* __restrict__ ET, float* __restrict__ out) {
  __shared__ float sA[64][132];   // k-major A tile, padded (132*4B = 16B-aligned rows)
  __shared__ float sB[64][68];    // k-major B tile, padded (68*4B  = 16B-aligned rows)
  int bid  = blockIdx.x;
  int pair = bid >> 8;
  int rem  = bid & 255;
  int ib   = rem >> 2;
  int js   = rem & 3;
  const float* et = ET + (size_t)pair * ET_ELEMS;
  int i0    = ib * BM;
  int jbase = js * JCHUNK;
  int tid = threadIdx.x;
  int tx = tid & 15;              // j micro index (4 cols)
  int ty = tid >> 4;              // i micro index (8 rows)

  // stage A tile once: 64 k-rows x 128 i-floats, coalesced float4
  {
    int f  = tid & 31;
    int kr = tid >> 5;            // 8 k-rows per pass
    #pragma unroll
    for (int r = 0; r < 8; ++r) {
      int k = kr + r * 8;
      float4 v = *reinterpret_cast<const float4*>(&et[(size_t)k * BROWS + i0 + f * 4]);
      *reinterpret_cast<float4*>(&sA[k][f * 4]) = v;
    }
  }

  float rowsum[8];
  #pragma unroll
  for (int m = 0; m < 8; ++m) rowsum[m] = 0.f;

  for (int j = jbase; j < jbase + JCHUNK; j += BN) {
    __syncthreads();              // protect sB from previous iteration's readers
    {
      int f  = tid & 15;
      int kr = tid >> 4;          // 16 k-rows per pass
      #pragma unroll
      for (int r = 0; r < 4; ++r) {
        int k = kr + r * 16;
        float4 v = *reinterpret_cast<const float4*>(&et[(size_t)k * BROWS + j + f * 4]);
        *reinterpret_cast<float4*>(&sB[k][f * 4]) = v;
      }
    }
    __syncthreads();

    float acc[8][4];
    #pragma unroll
    for (int m = 0; m < 8; ++m)
      #pragma unroll
      for (int nn = 0; nn < 4; ++nn) acc[m][nn] = 0.f;

    #pragma unroll 8
    for (int k = 0; k < 64; ++k) {
      float4 a0 = *reinterpret_cast<const float4*>(&sA[k][ty * 8]);
      float4 a1 = *reinterpret_cast<const float4*>(&sA[k][ty * 8 + 4]);
      float4 bv = *reinterpret_cast<const float4*>(&sB[k][tx * 4]);
      float am[8] = {a0.x, a0.y, a0.z, a0.w, a1.x, a1.y, a1.z, a1.w};
      float bn[4] = {bv.x, bv.y, bv.z, bv.w};
      #pragma unroll
      for (int m = 0; m < 8; ++m)
        #pragma unroll
        for (int nn = 0; nn < 4; ++nn)
          acc[m][nn] += am[m] * bn[nn];
    }

    #pragma unroll
    for (int m = 0; m < 8; ++m)
      #pragma unroll
      for (int nn = 0; nn < 4; ++nn) {
        float q = acc[m][nn];
        float f = sqrtf(q);
        rowsum[m] += (q < 0.f) ? 0.f : f;
      }
  }

  // reduce the 16 tx-partials (lane bits 0..3 within the wave)
  #pragma unroll
  for (int m = 0; m < 8; ++m) {
    float v = rowsum[m];
    v += __shfl_xor(v, 1);
    v += __shfl_xor(v, 2);
    v += __shfl_xor(v, 4);
    v += __shfl_xor(v, 8);
    rowsum[m] = v;
  }
  if (tx == 0) {
    #pragma unroll
    for (int m = 0; m < 8; ++m)
      atomicAdd(&out[pair * BROWS + i0 + ty * 8 + m],
                rowsum[m] + (float)JCHUNK * EPS_OUT);
  }
}

// ---------------------------------------------------------------------------
extern "C" void kernel_launch(void* const* d_in, const int* in_sizes, int n_in,
                              void* d_out, int out_size, void* d_ws, size_t ws_size,
                              hipStream_t stream) {
  const float* anchor   = (const float*)d_in[0];
  const float* positive = (const float*)d_in[1];
  const float* negative = (const float*)d_in[2];
  float* out = (float*)d_out;
  float* ws  = (float*)d_ws;

  float* stats   = ws + WS_STATS;
  float* inv_std = ws + WS_INVSTD;
  float* ET      = ws + WS_ET;

  // zero stats + output (harness poisons them with 0xAA)
  hipMemsetAsync(stats, 0, 384 * sizeof(float), stream);
  hipMemsetAsync(out, 0, (size_t)out_size * sizeof(float), stream);

  stats_kernel<<<128, 256, 0, stream>>>(anchor, positive, negative, stats);
  invstd_kernel<<<1, 64, 0, stream>>>(stats, inv_std);
  diff_kernel<<<256, 256, 0, stream>>>(anchor, positive, negative, inv_std, ET);
  mdist_kernel<<<512, 256, 0, stream>>>(ET, out);
}

// Round 2
// 247.405 us; speedup vs baseline: 1.3441x; 1.3441x over previous
//
#include <hip/hip_runtime.h>
#include <hip/hip_bf16.h>

// MahalanobisDistanceLayer: B=8192, D=64.
// q = E @ E^T with E = (a-b) * rsqrt(var_per_feature(concat(a,b)+eps));
// out[i] = sum_j (q<0 ? 0 : sqrt(q)) + B*EPS_OUT for (anchor,positive), (anchor,negative).
//
// Split-bf16 path: E = Ehi + Elo (both bf16). q ~= Ehi*Ehi^T + Ehi*Elo^T + Elo*Ehi^T
// -> one GEMM with K=192 on the MFMA pipe (bf16 products are exact in fp32 accum).

typedef short bf16x8 __attribute__((ext_vector_type(8)));
typedef float f32x4 __attribute__((ext_vector_type(4)));

#define BROWS 8192
#define DFEAT 64
#define NCO   16384
#define EPS_IN  1e-4f
#define EPS_OUT 1e-6f

// ---- workspace layout ----
// floats [0,128)        : inv_std (pair0 64, pair1 64)   -- persists
// ushorts at ws+128f    : EHL, 2 pairs x 8192 rows x 128 bf16 (row = [hi(64)|lo(64)], 256B)
//                         16B-chunk index XOR-swizzled by (row&7)  [G4 swizzle, pre-applied]
// floats [1024, 50176)  : stats partials (128 blocks x 384) -- dead before prep overwrites (stream order)
#define WS_INVSTD 0
#define WS_EHL_F  128
#define WS_PART_F 1024
#define EHL_PAIR_USHORTS ((size_t)BROWS * 128)

static __device__ inline unsigned short f2bf_rne(float x) {
  unsigned u = __float_as_uint(x);
  unsigned r = (u + 0x7FFF + ((u >> 16) & 1)) >> 16;
  return (unsigned short)r;
}
static __device__ inline float bf2f(unsigned short s) {
  return __uint_as_float(((unsigned)s) << 16);
}

// ---------------------------------------------------------------------------
// Kernel A: per-feature partial sums / sums-of-squares (per block, no global atomics).
__global__ __launch_bounds__(256) void stats_kernel(
    const float* __restrict__ a, const float* __restrict__ p,
    const float* __restrict__ n, float* __restrict__ part) {
  __shared__ float acc[6][64];
  int tid = threadIdx.x;
  if (tid < 64) {
    #pragma unroll
    for (int g = 0; g < 6; ++g) acc[g][tid] = 0.f;
  }
  __syncthreads();
  int d  = tid & 63;
  int rg = tid >> 6;
  int row0 = blockIdx.x * 64;
  float sa = 0.f, qa = 0.f, sp = 0.f, qp = 0.f, sn = 0.f, qn = 0.f;
  for (int r = rg; r < 64; r += 4) {
    int idx = (row0 + r) * DFEAT + d;
    float va = a[idx] + EPS_IN; sa += va; qa += va * va;
    float vp = p[idx] + EPS_IN; sp += vp; qp += vp * vp;
    float vn = n[idx] + EPS_IN; sn += vn; qn += vn * vn;
  }
  atomicAdd(&acc[0][d], sa); atomicAdd(&acc[1][d], qa);
  atomicAdd(&acc[2][d], sp); atomicAdd(&acc[3][d], qp);
  atomicAdd(&acc[4][d], sn); atomicAdd(&acc[5][d], qn);
  __syncthreads();
  for (int v = tid; v < 384; v += 256)
    part[blockIdx.x * 384 + v] = acc[v >> 6][v & 63];
}

// ---------------------------------------------------------------------------
// Kernel A2: reduce partials -> inv_std[pair][d] = 1/sqrt(var). 1 block x 256.
__global__ __launch_bounds__(256) void invstd_kernel(
    const float* __restrict__ part, float* __restrict__ inv_std) {
  __shared__ float red[4][6][64];
  int tid = threadIdx.x;
  int d = tid & 63, bg = tid >> 6;
  float s[6] = {0.f, 0.f, 0.f, 0.f, 0.f, 0.f};
  for (int b = bg; b < 128; b += 4) {
    const float* pp = part + b * 384;
    #pragma unroll
    for (int g = 0; g < 6; ++g) s[g] += pp[g * 64 + d];
  }
  #pragma unroll
  for (int g = 0; g < 6; ++g) red[bg][g][d] = s[g];
  __syncthreads();
  if (tid < 64) {
    float t[6];
    #pragma unroll
    for (int g = 0; g < 6; ++g)
      t[g] = red[0][g][d] + red[1][g][d] + red[2][g][d] + red[3][g][d];
    const float invN = 1.0f / (float)NCO;
    float m1 = (t[0] + t[2]) * invN;
    float v1 = (t[1] + t[3]) * invN - m1 * m1;
    float m2 = (t[0] + t[4]) * invN;
    float v2 = (t[1] + t[5]) * invN - m2 * m2;
    inv_std[d]      = 1.0f / sqrtf(v1);
    inv_std[64 + d] = 1.0f / sqrtf(v2);
  }
}

// ---------------------------------------------------------------------------
// Kernel B: build EHL[pair][row][j'] bf16 rows [hi|lo], 16B-chunk XOR-swizzled.
// j' = (half<<6) | (d ^ ((row&7)<<3))
__global__ __launch_bounds__(256) void prep_kernel(
    const float* __restrict__ a, const float* __restrict__ p,
    const float* __restrict__ n, const float* __restrict__ inv_std,
    unsigned short* __restrict__ EHL) {
  int pair = blockIdx.x >> 7;
  int tb   = blockIdx.x & 127;
  const float* bptr = pair ? n : p;
  float is = inv_std[pair * 64 + (threadIdx.x & 63)];
  unsigned short* dst = EHL + (size_t)pair * EHL_PAIR_USHORTS;
  int d  = threadIdx.x & 63;
  int rg = threadIdx.x >> 6;
  for (int r = rg; r < 64; r += 4) {
    int row = tb * 64 + r;
    int idx = row * DFEAT + d;
    float e = (a[idx] - bptr[idx]) * is;
    unsigned short hi = f2bf_rne(e);
    unsigned short lo = f2bf_rne(e - bf2f(hi));
    int js = d ^ ((row & 7) << 3);
    dst[(size_t)row * 128 + js]      = hi;
    dst[(size_t)row * 128 + 64 + js] = lo;
  }
}

// ---------------------------------------------------------------------------
// Kernel C: MFMA GEMM. 128x128 tile/block, 4 waves of 64x64, K=3x64 products.
// Grid: 2 pairs x 64 ib x 64 jb = 8192 blocks, 256 threads.
__global__ __launch_bounds__(256) void mdist_mfma(
    const unsigned short* __restrict__ EHL, float* __restrict__ out) {
  __shared__ __align__(16) unsigned char sA[128 * 256];
  __shared__ __align__(16) unsigned char sB[128 * 256];
  int bid  = blockIdx.x;
  int pair = bid >> 12;
  int rem  = bid & 4095;
  int ib   = rem >> 6;
  int jb   = rem & 63;
  const char* base = (const char*)(EHL + (size_t)pair * EHL_PAIR_USHORTS);
  const char* gA = base + (size_t)ib * 128 * 256;
  const char* gB = base + (size_t)jb * 128 * 256;
  int tid = threadIdx.x;

  // stage 2x32KB via direct global->LDS (global pre-swizzled, LDS dest linear)
  #pragma unroll
  for (int ph = 0; ph < 8; ++ph) {
    int off = ph * 4096 + tid * 16;
    __builtin_amdgcn_global_load_lds(
        (const __attribute__((address_space(1))) void*)(gA + off),
        (__attribute__((address_space(3))) void*)(sA + off), 16, 0, 0);
    __builtin_amdgcn_global_load_lds(
        (const __attribute__((address_space(1))) void*)(gB + off),
        (__attribute__((address_space(3))) void*)(sB + off), 16, 0, 0);
  }
  __syncthreads();   // compiler drains vmcnt before s_barrier

  int lane = tid & 63, w = tid >> 6;
  int wr = w >> 1, wc = w & 1;
  int l15 = lane & 15, lg = lane >> 4;

  f32x4 zero = {0.f, 0.f, 0.f, 0.f};
  f32x4 acc[4][4];
  #pragma unroll
  for (int m = 0; m < 4; ++m)
    #pragma unroll
    for (int n = 0; n < 4; ++n) acc[m][n] = zero;

  // product terms t: (A-half, B-half) = (hi,hi), (hi,lo), (lo,hi)
  const int AH[3] = {0, 0, 1};
  const int BH[3] = {0, 1, 0};
  #pragma unroll
  for (int t = 0; t < 3; ++t) {
    #pragma unroll
    for (int ks = 0; ks < 2; ++ks) {
      bf16x8 af[4], bf[4];
      #pragma unroll
      for (int m = 0; m < 4; ++m) {
        int r = wr * 64 + m * 16 + l15;
        int c = (AH[t] << 3) | (ks << 2) | lg;
        int cs = c ^ (r & 7);
        af[m] = *(const bf16x8*)(sA + r * 256 + cs * 16);
      }
      #pragma unroll
      for (int n = 0; n < 4; ++n) {
        int r = wc * 64 + n * 16 + l15;
        int c = (BH[t] << 3) | (ks << 2) | lg;
        int cs = c ^ (r & 7);
        bf[n] = *(const bf16x8*)(sB + r * 256 + cs * 16);
      }
      #pragma unroll
      for (int m = 0; m < 4; ++m)
        #pragma unroll
        for (int n = 0; n < 4; ++n)
          acc[m][n] = __builtin_amdgcn_mfma_f32_16x16x32_bf16(
              af[m], bf[n], acc[m][n], 0, 0, 0);
    }
  }

  // epilogue: mask+sqrt, sum over the 64 cols this wave owns
  float rs[4][4];
  #pragma unroll
  for (int m = 0; m < 4; ++m)
    #pragma unroll
    for (int r = 0; r < 4; ++r) rs[m][r] = 0.f;
  #pragma unroll
  for (int m = 0; m < 4; ++m)
    #pragma unroll
    for (int n = 0; n < 4; ++n)
      #pragma unroll
      for (int r = 0; r < 4; ++r) {
        float q = acc[m][n][r];
        float f = sqrtf(q);
        rs[m][r] += (q < 0.f) ? 0.f : f;
      }
  #pragma unroll
  for (int m = 0; m < 4; ++m)
    #pragma unroll
    for (int r = 0; r < 4; ++r) {
      float v = rs[m][r];
      v += __shfl_xor(v, 1);
      v += __shfl_xor(v, 2);
      v += __shfl_xor(v, 4);
      v += __shfl_xor(v, 8);
      rs[m][r] = v;
    }
  if (l15 == 0) {
    int i0 = ib * 128;
    #pragma unroll
    for (int m = 0; m < 4; ++m)
      #pragma unroll
      for (int r = 0; r < 4; ++r)
        atomicAdd(&out[pair * BROWS + i0 + wr * 64 + m * 16 + lg * 4 + r],
                  rs[m][r] + 64.f * EPS_OUT);
  }
}

// ---------------------------------------------------------------------------
extern "C" void kernel_launch(void* const* d_in, const int* in_sizes, int n_in,
                              void* d_out, int out_size, void* d_ws, size_t ws_size,
                              hipStream_t stream) {
  const float* anchor   = (const float*)d_in[0];
  const float* positive = (const float*)d_in[1];
  const float* negative = (const float*)d_in[2];
  float* out = (float*)d_out;
  float* ws  = (float*)d_ws;

  float* inv_std = ws + WS_INVSTD;
  float* part    = ws + WS_PART_F;                       // dead before EHL's region is written
  unsigned short* EHL = (unsigned short*)(ws + WS_EHL_F);

  hipMemsetAsync(out, 0, (size_t)out_size * sizeof(float), stream);

  stats_kernel<<<128, 256, 0, stream>>>(anchor, positive, negative, part);
  invstd_kernel<<<1, 256, 0, stream>>>(part, inv_std);
  prep_kernel<<<256, 256, 0, stream>>>(anchor, positive, negative, inv_std, EHL);
  mdist_mfma<<<8192, 256, 0, stream>>>(EHL, out);
}

// Round 4
// 201.432 us; speedup vs baseline: 1.6509x; 1.2282x over previous
//
#include <hip/hip_runtime.h>
#include <hip/hip_bf16.h>

// MahalanobisDistanceLayer: B=8192, D=64.
// q = E @ E^T with E = (a-b) * rsqrt(var_per_feature(concat(a,b)+eps));
// out[i] = sum_j (q<0 ? 0 : sqrt(q)) + B*EPS_OUT for (anchor,positive), (anchor,negative).
//
// Split-bf16: E = Ehi + Elo. q ~= Ehi*Ehi^T + Ehi*Elo^T + Elo*Ehi^T -> K=192 bf16 GEMM.
// mdist: persistent-A-in-registers + double-buffered streamed B; masked-sqrt applied
// PER j-tile (step-local accumulator) -- the nonlinearity does not commute with K-accum.

typedef short bf16x8 __attribute__((ext_vector_type(8)));
typedef unsigned short u16x8 __attribute__((ext_vector_type(8)));
typedef float f32x4 __attribute__((ext_vector_type(4)));

#define BROWS 8192
#define DFEAT 64
#define NCO   16384
#define EPS_IN  1e-4f
#define EPS_OUT 1e-6f
#define NSTEP 32              // B tiles per block (64 rows each -> 2048 j-cols)

// ---- workspace layout ----
// floats [0,128)     : inv_std (pair0 64, pair1 64)
// ushorts at ws+128f : EHL, 2 pairs x 8192 rows x 128 bf16 (row = [hi(64)|lo(64)], 256B)
//                      16B-chunk index XOR-swizzled by (row&7)
// floats [1024, ...) : stats partials (128 x 384) -- consumed by invstd before prep overwrites
#define WS_INVSTD 0
#define WS_EHL_F  128
#define WS_PART_F 1024
#define EHL_PAIR_USHORTS ((size_t)BROWS * 128)

static __device__ inline unsigned short f2bf_rne(float x) {
  unsigned u = __float_as_uint(x);
  unsigned r = (u + 0x7FFF + ((u >> 16) & 1)) >> 16;
  return (unsigned short)r;
}
static __device__ inline float bf2f(unsigned short s) {
  return __uint_as_float(((unsigned)s) << 16);
}

// ---------------------------------------------------------------------------
// Kernel A: per-feature partial sums / sums-of-squares.
__global__ __launch_bounds__(256) void stats_kernel(
    const float* __restrict__ a, const float* __restrict__ p,
    const float* __restrict__ n, float* __restrict__ part) {
  __shared__ float acc[6][64];
  int tid = threadIdx.x;
  if (tid < 64) {
    #pragma unroll
    for (int g = 0; g < 6; ++g) acc[g][tid] = 0.f;
  }
  __syncthreads();
  int d  = tid & 63;
  int rg = tid >> 6;
  int row0 = blockIdx.x * 64;
  float sa = 0.f, qa = 0.f, sp = 0.f, qp = 0.f, sn = 0.f, qn = 0.f;
  for (int r = rg; r < 64; r += 4) {
    int idx = (row0 + r) * DFEAT + d;
    float va = a[idx] + EPS_IN; sa += va; qa += va * va;
    float vp = p[idx] + EPS_IN; sp += vp; qp += vp * vp;
    float vn = n[idx] + EPS_IN; sn += vn; qn += vn * vn;
  }
  atomicAdd(&acc[0][d], sa); atomicAdd(&acc[1][d], qa);
  atomicAdd(&acc[2][d], sp); atomicAdd(&acc[3][d], qp);
  atomicAdd(&acc[4][d], sn); atomicAdd(&acc[5][d], qn);
  __syncthreads();
  for (int v = tid; v < 384; v += 256)
    part[blockIdx.x * 384 + v] = acc[v >> 6][v & 63];
}

// ---------------------------------------------------------------------------
// Kernel A2: reduce partials -> inv_std. 1 block x 256.
__global__ __launch_bounds__(256) void invstd_kernel(
    const float* __restrict__ part, float* __restrict__ inv_std) {
  __shared__ float red[4][6][64];
  int tid = threadIdx.x;
  int d = tid & 63, bg = tid >> 6;
  float s[6] = {0.f, 0.f, 0.f, 0.f, 0.f, 0.f};
  for (int b = bg; b < 128; b += 4) {
    const float* pp = part + b * 384;
    #pragma unroll
    for (int g = 0; g < 6; ++g) s[g] += pp[g * 64 + d];
  }
  #pragma unroll
  for (int g = 0; g < 6; ++g) red[bg][g][d] = s[g];
  __syncthreads();
  if (tid < 64) {
    float t[6];
    #pragma unroll
    for (int g = 0; g < 6; ++g)
      t[g] = red[0][g][d] + red[1][g][d] + red[2][g][d] + red[3][g][d];
    const float invN = 1.0f / (float)NCO;
    float m1 = (t[0] + t[2]) * invN;
    float v1 = (t[1] + t[3]) * invN - m1 * m1;
    float m2 = (t[0] + t[4]) * invN;
    float v2 = (t[1] + t[5]) * invN - m2 * m2;
    inv_std[d]      = 1.0f / sqrtf(v1);
    inv_std[64 + d] = 1.0f / sqrtf(v2);
  }
}

// ---------------------------------------------------------------------------
// Kernel B: build EHL rows [hi(64)|lo(64)] bf16, 16B chunks XOR-swizzled by row&7.
// Each thread produces two 16B chunks (one hi, one lo).
// Grid: 2 pairs x 256 row-tiles (32 rows each) = 512 blocks x 256 threads.
__global__ __launch_bounds__(256) void prep_kernel(
    const float* __restrict__ a, const float* __restrict__ p,
    const float* __restrict__ n, const float* __restrict__ inv_std,
    unsigned short* __restrict__ EHL) {
  __shared__ float is_s[64];
  int pair = blockIdx.x >> 8;
  int tb   = blockIdx.x & 255;
  int tid  = threadIdx.x;
  if (tid < 64) is_s[tid] = inv_std[pair * 64 + tid];
  __syncthreads();
  const float* bptr = pair ? n : p;
  unsigned short* dst = EHL + (size_t)pair * EHL_PAIR_USHORTS;
  int c0 = tid & 7;          // chunk within row (8 bf16 = 16B)
  int rl = tid >> 3;         // row within block (0..31)
  int row = tb * 32 + rl;
  int d0 = c0 * 8;
  const float* ar = a    + (size_t)row * DFEAT + d0;
  const float* br = bptr + (size_t)row * DFEAT + d0;
  float4 a0 = *(const float4*)(ar);
  float4 a1 = *(const float4*)(ar + 4);
  float4 b0 = *(const float4*)(br);
  float4 b1 = *(const float4*)(br + 4);
  float e[8] = {a0.x - b0.x, a0.y - b0.y, a0.z - b0.z, a0.w - b0.w,
                a1.x - b1.x, a1.y - b1.y, a1.z - b1.z, a1.w - b1.w};
  u16x8 vh, vl;
  #pragma unroll
  for (int j = 0; j < 8; ++j) {
    float ej = e[j] * is_s[d0 + j];
    unsigned short hi = f2bf_rne(ej);
    vh[j] = hi;
    vl[j] = f2bf_rne(ej - bf2f(hi));
  }
  int cs = c0 ^ (row & 7);
  char* drow = (char*)dst + (size_t)row * 256;
  *(u16x8*)(drow + cs * 16)       = vh;   // hi chunk
  *(u16x8*)(drow + (8 + cs) * 16) = vl;   // lo chunk: (8+c0)^(row&7) = 8+cs
}

// ---------------------------------------------------------------------------
// Kernel C: MFMA GEMM, persistent A (registers) + double-buffered streamed B.
// 128 rows x 2048 cols per block; 4 waves (2x2), each 64x32 per step.
// Per-step: zero acc, 48 MFMAs (K=192), masked-sqrt into persistent rs.
// Grid: 2 pairs x 64 ib x 4 js = 512 blocks (= 2/CU), 256 threads.
#define GLOAD(gsrc, ldst)                                                  \
  __builtin_amdgcn_global_load_lds(                                        \
      (const __attribute__((address_space(1))) void*)(gsrc),               \
      (__attribute__((address_space(3))) void*)(ldst), 16, 0, 0)

__global__ __launch_bounds__(256, 2) void mdist_mfma(
    const unsigned short* __restrict__ EHL, float* __restrict__ out) {
  __shared__ __align__(16) unsigned char sA[32768];
  __shared__ __align__(16) unsigned char sB0[16384];
  __shared__ __align__(16) unsigned char sB1[16384];
  int bid = blockIdx.x;
  int sw  = (bid & 7) * 64 + (bid >> 3);     // bijective XCD swizzle (512 = 8*64)
  int pair = sw >> 8;
  int js   = (sw >> 6) & 3;
  int ib   = sw & 63;
  const char* base = (const char*)(EHL + (size_t)pair * EHL_PAIR_USHORTS);
  const char* gA = base + (size_t)ib * 32768;
  const char* gB = base + (size_t)js * (NSTEP * 16384);
  int tid = threadIdx.x;

  // prologue: stage A (32KB) + B step 0 (16KB)
  #pragma unroll
  for (int r = 0; r < 8; ++r) {
    int off = r * 4096 + tid * 16;
    GLOAD(gA + off, sA + off);
  }
  #pragma unroll
  for (int r = 0; r < 4; ++r) {
    int off = r * 4096 + tid * 16;
    GLOAD(gB + off, sB0 + off);
  }
  __syncthreads();

  int lane = tid & 63, w = tid >> 6;
  int wr = w >> 1, wc = w & 1;
  int l15 = lane & 15, lg = lane >> 4;

  // A fragments, resident for whole kernel: af[hk][m], hk = (half<<1)|ks
  bf16x8 af[4][4];
  #pragma unroll
  for (int hk = 0; hk < 4; ++hk) {
    int c = ((hk >> 1) << 3) | ((hk & 1) << 2) | lg;
    #pragma unroll
    for (int m = 0; m < 4; ++m) {
      int r = wr * 64 + m * 16 + l15;
      int cs = c ^ (r & 7);
      af[hk][m] = *(const bf16x8*)(sA + r * 256 + cs * 16);
    }
  }

  // persistent per-row partial sums (C/D rows: lg*4+r within each 16-row frag)
  float rs[4][4];
  #pragma unroll
  for (int m = 0; m < 4; ++m)
    #pragma unroll
    for (int r = 0; r < 4; ++r) rs[m][r] = 0.f;

  const int AH[3] = {0, 0, 1};
  const int BH[3] = {0, 1, 0};

#define MSTEP(SBR, SBW, SIDX, DO_STAGE)                                     \
  do {                                                                      \
    if (DO_STAGE) {                                                         \
      const char* gs = gB + (SIDX) * 16384;                                 \
      _Pragma("unroll")                                                     \
      for (int r = 0; r < 4; ++r) {                                         \
        int off = r * 4096 + tid * 16;                                      \
        GLOAD(gs + off, (SBW) + off);                                       \
      }                                                                     \
    }                                                                       \
    bf16x8 bf[4][2];                                                        \
    _Pragma("unroll")                                                       \
    for (int hk = 0; hk < 4; ++hk) {                                        \
      int c = ((hk >> 1) << 3) | ((hk & 1) << 2) | lg;                      \
      _Pragma("unroll")                                                     \
      for (int nn = 0; nn < 2; ++nn) {                                      \
        int r = wc * 32 + nn * 16 + l15;                                    \
        int cs = c ^ (r & 7);                                               \
        bf[hk][nn] = *(const bf16x8*)((SBR) + r * 256 + cs * 16);           \
      }                                                                     \
    }                                                                       \
    f32x4 zero = {0.f, 0.f, 0.f, 0.f};                                      \
    f32x4 acc[4][2];                                                        \
    _Pragma("unroll")                                                       \
    for (int m = 0; m < 4; ++m) { acc[m][0] = zero; acc[m][1] = zero; }     \
    _Pragma("unroll")                                                       \
    for (int t = 0; t < 3; ++t) {                                           \
      _Pragma("unroll")                                                     \
      for (int ks = 0; ks < 2; ++ks) {                                      \
        int ahk = (AH[t] << 1) | ks;                                        \
        int bhk = (BH[t] << 1) | ks;                                        \
        _Pragma("unroll")                                                   \
        for (int m = 0; m < 4; ++m) {                                       \
          _Pragma("unroll")                                                 \
          for (int nn = 0; nn < 2; ++nn)                                    \
            acc[m][nn] = __builtin_amdgcn_mfma_f32_16x16x32_bf16(           \
                af[ahk][m], bf[bhk][nn], acc[m][nn], 0, 0, 0);              \
        }                                                                   \
      }                                                                     \
    }                                                                       \
    _Pragma("unroll")                                                       \
    for (int m = 0; m < 4; ++m) {                                           \
      _Pragma("unroll")                                                     \
      for (int nn = 0; nn < 2; ++nn) {                                      \
        _Pragma("unroll")                                                   \
        for (int r = 0; r < 4; ++r) {                                       \
          float q = acc[m][nn][r];                                          \
          float f = sqrtf(q);                                               \
          rs[m][r] += (q < 0.f) ? 0.f : f;                                  \
        }                                                                   \
      }                                                                     \
    }                                                                       \
  } while (0)

  for (int ss = 0; ss < NSTEP; ss += 2) {
    MSTEP(sB0, sB1, ss + 1, true);             // read sB0, prefetch ss+1 -> sB1
    __syncthreads();
    MSTEP(sB1, sB0, ss + 2, (ss + 2) < NSTEP); // read sB1, prefetch ss+2 -> sB0
    __syncthreads();
  }
#undef MSTEP

  // final reduce over the 16 col-lanes, then one atomic per row per wave
  #pragma unroll
  for (int m = 0; m < 4; ++m)
    #pragma unroll
    for (int r = 0; r < 4; ++r) {
      float v = rs[m][r];
      v += __shfl_xor(v, 1);
      v += __shfl_xor(v, 2);
      v += __shfl_xor(v, 4);
      v += __shfl_xor(v, 8);
      rs[m][r] = v;
    }
  if (l15 == 0) {
    int i0 = ib * 128;
    #pragma unroll
    for (int m = 0; m < 4; ++m)
      #pragma unroll
      for (int r = 0; r < 4; ++r)
        atomicAdd(&out[pair * BROWS + i0 + wr * 64 + m * 16 + lg * 4 + r],
                  rs[m][r] + 1024.f * EPS_OUT);
  }
}

// ---------------------------------------------------------------------------
extern "C" void kernel_launch(void* const* d_in, const int* in_sizes, int n_in,
                              void* d_out, int out_size, void* d_ws, size_t ws_size,
                              hipStream_t stream) {
  const float* anchor   = (const float*)d_in[0];
  const float* positive = (const float*)d_in[1];
  const float* negative = (const float*)d_in[2];
  float* out = (float*)d_out;
  float* ws  = (float*)d_ws;

  float* inv_std = ws + WS_INVSTD;
  float* part    = ws + WS_PART_F;     // consumed by invstd before prep overwrites
  unsigned short* EHL = (unsigned short*)(ws + WS_EHL_F);

  hipMemsetAsync(out, 0, (size_t)out_size * sizeof(float), stream);

  stats_kernel<<<128, 256, 0, stream>>>(anchor, positive, negative, part);
  invstd_kernel<<<1, 256, 0, stream>>>(part, inv_std);
  prep_kernel<<<512, 256, 0, stream>>>(anchor, positive, negative, inv_std, EHL);
  mdist_mfma<<<512, 256, 0, stream>>>(EHL, out);
}

// Round 5
// 129.794 us; speedup vs baseline: 2.5621x; 1.5519x over previous
//
#include <hip/hip_runtime.h>
#include <hip/hip_bf16.h>

// MahalanobisDistanceLayer: B=8192, D=64.
// q = E @ E^T with E = (a-b) * rsqrt(var_per_feature(concat(a,b)+eps));
// out[i] = sum_j (q<0 ? 0 : sqrt(q)) + B*EPS_OUT for (anchor,positive), (anchor,negative).
//
// Split-bf16: E = Ehi + Elo. q ~= Ehi*Ehi^T + Ehi*Elo^T + Elo*Ehi^T -> K=192 bf16 GEMM.
// mdist: persistent-A-in-registers + double-buffered streamed B; masked-sqrt applied
// PER j-tile via sqrt(max(q,0)) on the raw v_sqrt_f32 pipe (3 VALU ops/element).

typedef short bf16x8 __attribute__((ext_vector_type(8)));
typedef unsigned short u16x8 __attribute__((ext_vector_type(8)));
typedef float f32x4 __attribute__((ext_vector_type(4)));

#define BROWS 8192
#define DFEAT 64
#define NCO   16384
#define EPS_IN  1e-4f
#define EPS_OUT 1e-6f
#define NSTEP 32              // B tiles per block (64 rows each -> 2048 j-cols)

// ---- workspace layout ----
// floats [0,128)     : inv_std (pair0 64, pair1 64)
// ushorts at ws+128f : EHL, 2 pairs x 8192 rows x 128 bf16 (row = [hi(64)|lo(64)], 256B)
//                      16B-chunk index XOR-swizzled by (row&7)
// floats [1024, ...) : stats partials (128 x 384) -- consumed by invstd before prep overwrites
#define WS_INVSTD 0
#define WS_EHL_F  128
#define WS_PART_F 1024
#define EHL_PAIR_USHORTS ((size_t)BROWS * 128)

static __device__ inline unsigned short f2bf_rne(float x) {
  unsigned u = __float_as_uint(x);
  unsigned r = (u + 0x7FFF + ((u >> 16) & 1)) >> 16;
  return (unsigned short)r;
}
static __device__ inline float bf2f(unsigned short s) {
  return __uint_as_float(((unsigned)s) << 16);
}

// ---------------------------------------------------------------------------
// Kernel A: per-feature partial sums / sums-of-squares.
__global__ __launch_bounds__(256) void stats_kernel(
    const float* __restrict__ a, const float* __restrict__ p,
    const float* __restrict__ n, float* __restrict__ part) {
  __shared__ float acc[6][64];
  int tid = threadIdx.x;
  if (tid < 64) {
    #pragma unroll
    for (int g = 0; g < 6; ++g) acc[g][tid] = 0.f;
  }
  __syncthreads();
  int d  = tid & 63;
  int rg = tid >> 6;
  int row0 = blockIdx.x * 64;
  float sa = 0.f, qa = 0.f, sp = 0.f, qp = 0.f, sn = 0.f, qn = 0.f;
  for (int r = rg; r < 64; r += 4) {
    int idx = (row0 + r) * DFEAT + d;
    float va = a[idx] + EPS_IN; sa += va; qa += va * va;
    float vp = p[idx] + EPS_IN; sp += vp; qp += vp * vp;
    float vn = n[idx] + EPS_IN; sn += vn; qn += vn * vn;
  }
  atomicAdd(&acc[0][d], sa); atomicAdd(&acc[1][d], qa);
  atomicAdd(&acc[2][d], sp); atomicAdd(&acc[3][d], qp);
  atomicAdd(&acc[4][d], sn); atomicAdd(&acc[5][d], qn);
  __syncthreads();
  for (int v = tid; v < 384; v += 256)
    part[blockIdx.x * 384 + v] = acc[v >> 6][v & 63];
}

// ---------------------------------------------------------------------------
// Kernel A2: reduce partials -> inv_std. 1 block x 256.
__global__ __launch_bounds__(256) void invstd_kernel(
    const float* __restrict__ part, float* __restrict__ inv_std) {
  __shared__ float red[4][6][64];
  int tid = threadIdx.x;
  int d = tid & 63, bg = tid >> 6;
  float s[6] = {0.f, 0.f, 0.f, 0.f, 0.f, 0.f};
  for (int b = bg; b < 128; b += 4) {
    const float* pp = part + b * 384;
    #pragma unroll
    for (int g = 0; g < 6; ++g) s[g] += pp[g * 64 + d];
  }
  #pragma unroll
  for (int g = 0; g < 6; ++g) red[bg][g][d] = s[g];
  __syncthreads();
  if (tid < 64) {
    float t[6];
    #pragma unroll
    for (int g = 0; g < 6; ++g)
      t[g] = red[0][g][d] + red[1][g][d] + red[2][g][d] + red[3][g][d];
    const float invN = 1.0f / (float)NCO;
    float m1 = (t[0] + t[2]) * invN;
    float v1 = (t[1] + t[3]) * invN - m1 * m1;
    float m2 = (t[0] + t[4]) * invN;
    float v2 = (t[1] + t[5]) * invN - m2 * m2;
    inv_std[d]      = 1.0f / sqrtf(v1);
    inv_std[64 + d] = 1.0f / sqrtf(v2);
  }
}

// ---------------------------------------------------------------------------
// Kernel B: build EHL rows [hi(64)|lo(64)] bf16, 16B chunks XOR-swizzled by row&7.
// Also zeroes the output array (32 floats per block) so mdist can atomicAdd.
// Grid: 2 pairs x 256 row-tiles (32 rows each) = 512 blocks x 256 threads.
__global__ __launch_bounds__(256) void prep_kernel(
    const float* __restrict__ a, const float* __restrict__ p,
    const float* __restrict__ n, const float* __restrict__ inv_std,
    unsigned short* __restrict__ EHL, float* __restrict__ out) {
  __shared__ float is_s[64];
  int pair = blockIdx.x >> 8;
  int tb   = blockIdx.x & 255;
  int tid  = threadIdx.x;
  if (tid < 32) out[blockIdx.x * 32 + tid] = 0.f;     // 512*32 = 16384 = out_size
  if (tid < 64) is_s[tid] = inv_std[pair * 64 + tid];
  __syncthreads();
  const float* bptr = pair ? n : p;
  unsigned short* dst = EHL + (size_t)pair * EHL_PAIR_USHORTS;
  int c0 = tid & 7;          // chunk within row (8 bf16 = 16B)
  int rl = tid >> 3;         // row within block (0..31)
  int row = tb * 32 + rl;
  int d0 = c0 * 8;
  const float* ar = a    + (size_t)row * DFEAT + d0;
  const float* br = bptr + (size_t)row * DFEAT + d0;
  float4 a0 = *(const float4*)(ar);
  float4 a1 = *(const float4*)(ar + 4);
  float4 b0 = *(const float4*)(br);
  float4 b1 = *(const float4*)(br + 4);
  float e[8] = {a0.x - b0.x, a0.y - b0.y, a0.z - b0.z, a0.w - b0.w,
                a1.x - b1.x, a1.y - b1.y, a1.z - b1.z, a1.w - b1.w};
  u16x8 vh, vl;
  #pragma unroll
  for (int j = 0; j < 8; ++j) {
    float ej = e[j] * is_s[d0 + j];
    unsigned short hi = f2bf_rne(ej);
    vh[j] = hi;
    vl[j] = f2bf_rne(ej - bf2f(hi));
  }
  int cs = c0 ^ (row & 7);
  char* drow = (char*)dst + (size_t)row * 256;
  *(u16x8*)(drow + cs * 16)       = vh;   // hi chunk
  *(u16x8*)(drow + (8 + cs) * 16) = vl;   // lo chunk: (8+c0)^(row&7) = 8+cs
}

// ---------------------------------------------------------------------------
// Kernel C: MFMA GEMM, persistent A (registers) + double-buffered streamed B.
// 128 rows x 2048 cols per block; 4 waves (2x2), each 64x32 per step.
// Per-step: 48 MFMAs (K=192, zero-C on first), sqrt(max(q,0)) into persistent rs.
// Grid: 2 pairs x 64 ib x 4 js = 512 blocks (= 2/CU), 256 threads.
#define GLOAD(gsrc, ldst)                                                  \
  __builtin_amdgcn_global_load_lds(                                        \
      (const __attribute__((address_space(1))) void*)(gsrc),               \
      (__attribute__((address_space(3))) void*)(ldst), 16, 0, 0)

__global__ __launch_bounds__(256, 2) void mdist_mfma(
    const unsigned short* __restrict__ EHL, float* __restrict__ out) {
  __shared__ __align__(16) unsigned char sA[32768];
  __shared__ __align__(16) unsigned char sB0[16384];
  __shared__ __align__(16) unsigned char sB1[16384];
  int bid = blockIdx.x;
  int sw  = (bid & 7) * 64 + (bid >> 3);     // bijective XCD swizzle (512 = 8*64)
  int pair = sw >> 8;
  int js   = (sw >> 6) & 3;
  int ib   = sw & 63;
  const char* base = (const char*)(EHL + (size_t)pair * EHL_PAIR_USHORTS);
  const char* gA = base + (size_t)ib * 32768;
  const char* gB = base + (size_t)js * (NSTEP * 16384);
  int tid = threadIdx.x;

  // prologue: stage A (32KB) + B step 0 (16KB)
  #pragma unroll
  for (int r = 0; r < 8; ++r) {
    int off = r * 4096 + tid * 16;
    GLOAD(gA + off, sA + off);
  }
  #pragma unroll
  for (int r = 0; r < 4; ++r) {
    int off = r * 4096 + tid * 16;
    GLOAD(gB + off, sB0 + off);
  }
  __syncthreads();

  int lane = tid & 63, w = tid >> 6;
  int wr = w >> 1, wc = w & 1;
  int l15 = lane & 15, lg = lane >> 4;

  // A fragments, resident for whole kernel: af[hk][m], hk = (half<<1)|ks
  bf16x8 af[4][4];
  #pragma unroll
  for (int hk = 0; hk < 4; ++hk) {
    int c = ((hk >> 1) << 3) | ((hk & 1) << 2) | lg;
    #pragma unroll
    for (int m = 0; m < 4; ++m) {
      int r = wr * 64 + m * 16 + l15;
      int cs = c ^ (r & 7);
      af[hk][m] = *(const bf16x8*)(sA + r * 256 + cs * 16);
    }
  }

  // persistent per-row partial sums (C/D rows: lg*4+r within each 16-row frag)
  float rs[4][4];
  #pragma unroll
  for (int m = 0; m < 4; ++m)
    #pragma unroll
    for (int r = 0; r < 4; ++r) rs[m][r] = 0.f;

  const f32x4 zacc = {0.f, 0.f, 0.f, 0.f};
  const int AH[3] = {0, 0, 1};
  const int BH[3] = {0, 1, 0};

#define MSTEP(SBR, SBW, SIDX, DO_STAGE)                                     \
  do {                                                                      \
    if (DO_STAGE) {                                                         \
      const char* gs = gB + (SIDX) * 16384;                                 \
      _Pragma("unroll")                                                     \
      for (int r = 0; r < 4; ++r) {                                         \
        int off = r * 4096 + tid * 16;                                      \
        GLOAD(gs + off, (SBW) + off);                                       \
      }                                                                     \
    }                                                                       \
    bf16x8 bf[4][2];                                                        \
    _Pragma("unroll")                                                       \
    for (int hk = 0; hk < 4; ++hk) {                                        \
      int c = ((hk >> 1) << 3) | ((hk & 1) << 2) | lg;                      \
      _Pragma("unroll")                                                     \
      for (int nn = 0; nn < 2; ++nn) {                                      \
        int r = wc * 32 + nn * 16 + l15;                                    \
        int cs = c ^ (r & 7);                                               \
        bf[hk][nn] = *(const bf16x8*)((SBR) + r * 256 + cs * 16);           \
      }                                                                     \
    }                                                                       \
    f32x4 acc[4][2];                                                        \
    _Pragma("unroll")                                                       \
    for (int t = 0; t < 3; ++t) {                                           \
      _Pragma("unroll")                                                     \
      for (int ks = 0; ks < 2; ++ks) {                                      \
        int ahk = (AH[t] << 1) | ks;                                        \
        int bhk = (BH[t] << 1) | ks;                                        \
        _Pragma("unroll")                                                   \
        for (int m = 0; m < 4; ++m) {                                       \
          _Pragma("unroll")                                                 \
          for (int nn = 0; nn < 2; ++nn)                                    \
            acc[m][nn] = __builtin_amdgcn_mfma_f32_16x16x32_bf16(           \
                af[ahk][m], bf[bhk][nn],                                    \
                (t == 0 && ks == 0) ? zacc : acc[m][nn], 0, 0, 0);          \
        }                                                                   \
      }                                                                     \
    }                                                                       \
    _Pragma("unroll")                                                       \
    for (int m = 0; m < 4; ++m) {                                           \
      _Pragma("unroll")                                                     \
      for (int nn = 0; nn < 2; ++nn) {                                      \
        _Pragma("unroll")                                                   \
        for (int r = 0; r < 4; ++r) {                                       \
          float q = acc[m][nn][r];                                          \
          rs[m][r] += __builtin_amdgcn_sqrtf(fmaxf(q, 0.f));                \
        }                                                                   \
      }                                                                     \
    }                                                                       \
  } while (0)

  for (int ss = 0; ss < NSTEP; ss += 2) {
    MSTEP(sB0, sB1, ss + 1, true);             // read sB0, prefetch ss+1 -> sB1
    __syncthreads();
    MSTEP(sB1, sB0, ss + 2, (ss + 2) < NSTEP); // read sB1, prefetch ss+2 -> sB0
    __syncthreads();
  }
#undef MSTEP

  // final reduce over the 16 col-lanes, then one atomic per row per wave
  #pragma unroll
  for (int m = 0; m < 4; ++m)
    #pragma unroll
    for (int r = 0; r < 4; ++r) {
      float v = rs[m][r];
      v += __shfl_xor(v, 1);
      v += __shfl_xor(v, 2);
      v += __shfl_xor(v, 4);
      v += __shfl_xor(v, 8);
      rs[m][r] = v;
    }
  if (l15 == 0) {
    int i0 = ib * 128;
    #pragma unroll
    for (int m = 0; m < 4; ++m)
      #pragma unroll
      for (int r = 0; r < 4; ++r)
        atomicAdd(&out[pair * BROWS + i0 + wr * 64 + m * 16 + lg * 4 + r],
                  rs[m][r] + 1024.f * EPS_OUT);
  }
}

// ---------------------------------------------------------------------------
extern "C" void kernel_launch(void* const* d_in, const int* in_sizes, int n_in,
                              void* d_out, int out_size, void* d_ws, size_t ws_size,
                              hipStream_t stream) {
  const float* anchor   = (const float*)d_in[0];
  const float* positive = (const float*)d_in[1];
  const float* negative = (const float*)d_in[2];
  float* out = (float*)d_out;
  float* ws  = (float*)d_ws;

  float* inv_std = ws + WS_INVSTD;
  float* part    = ws + WS_PART_F;     // consumed by invstd before prep overwrites
  unsigned short* EHL = (unsigned short*)(ws + WS_EHL_F);

  stats_kernel<<<128, 256, 0, stream>>>(anchor, positive, negative, part);
  invstd_kernel<<<1, 256, 0, stream>>>(part, inv_std);
  prep_kernel<<<512, 256, 0, stream>>>(anchor, positive, negative, inv_std, EHL, out);
  mdist_mfma<<<512, 256, 0, stream>>>(EHL, out);
}

// Round 6
// 108.877 us; speedup vs baseline: 3.0543x; 1.1921x over previous
//
#include <hip/hip_runtime.h>
#include <hip/hip_bf16.h>

// MahalanobisDistanceLayer: B=8192, D=64.
// q = E @ E^T with E = (a-b) * rsqrt(var_per_feature(concat(a,b)+eps));
// out[i] = sum_j (q<0 ? 0 : sqrt(q)) + B*EPS_OUT for (anchor,positive), (anchor,negative).
//
// Split-bf16: E = Ehi + Elo. q ~= Ehi*Ehi^T + Ehi*Elo^T + Elo*Ehi^T -> K=192 bf16 GEMM.
// Symmetric scheme: per pair, 64 tiles of 128 rows; block (pair, ib, half) processes
// s = half, half+2, ... (jb = (ib+s) & 63). s=0 diag tile: row-sums only. s>0: row-sums
// to out[ib rows] AND col-sums to out[jb rows] (f(q) symmetric) -> half the FLOPs.

typedef short bf16x8 __attribute__((ext_vector_type(8)));
typedef unsigned short u16x8 __attribute__((ext_vector_type(8)));
typedef float f32x4 __attribute__((ext_vector_type(4)));

#define BROWS 8192
#define DFEAT 64
#define NCO   16384
#define EPS_IN  1e-4f
#define EPS_OUT 1e-6f

// ---- workspace layout (bytes) ----
// [0, 1536)      : stats, 6 groups x 64 floats (Sa,Qa,Sp,Qp,Sn,Qn), atomic-accumulated
// [2048, 2048+4MB) : EHL, 2 pairs x 8192 rows x 128 bf16 (row = [hi(64)|lo(64)], 256B)
//                    16B-chunk index XOR-swizzled by (row&7)
#define WS_EHL_F 512
#define EHL_PAIR_USHORTS ((size_t)BROWS * 128)

static __device__ inline unsigned short f2bf_rne(float x) {
  unsigned u = __float_as_uint(x);
  unsigned r = (u + 0x7FFF + ((u >> 16) & 1)) >> 16;
  return (unsigned short)r;
}
static __device__ inline float bf2f(unsigned short s) {
  return __uint_as_float(((unsigned)s) << 16);
}

// ---------------------------------------------------------------------------
// Kernel A: per-feature sums / sums-of-squares, float4 loads, atomic into stats[384].
// 256 blocks x 256 threads; each thread loads 2 float4 per array.
__global__ __launch_bounds__(256) void stats_kernel(
    const float* __restrict__ a, const float* __restrict__ p,
    const float* __restrict__ n, float* __restrict__ stats) {
  __shared__ float acc[6][64];
  int tid = threadIdx.x;
  for (int v = tid; v < 384; v += 256) acc[v >> 6][v & 63] = 0.f;
  __syncthreads();
  const float4* A4 = (const float4*)a;
  const float4* P4 = (const float4*)p;
  const float4* N4 = (const float4*)n;
  size_t base = (size_t)blockIdx.x * 512 + tid;
  float s[3][4] = {}, q[3][4] = {};
  #pragma unroll
  for (int k = 0; k < 2; ++k) {
    size_t idx = base + k * 256;
    float4 va = A4[idx], vp = P4[idx], vn = N4[idx];
    float ea[4] = {va.x, va.y, va.z, va.w};
    float ep[4] = {vp.x, vp.y, vp.z, vp.w};
    float en[4] = {vn.x, vn.y, vn.z, vn.w};
    #pragma unroll
    for (int f = 0; f < 4; ++f) {
      float x0 = ea[f] + EPS_IN; s[0][f] += x0; q[0][f] += x0 * x0;
      float x1 = ep[f] + EPS_IN; s[1][f] += x1; q[1][f] += x1 * x1;
      float x2 = en[f] + EPS_IN; s[2][f] += x2; q[2][f] += x2 * x2;
    }
  }
  // lanes t, t^16, t^32, t^48 share the same feature group d0 = 4*(t&15)
  #pragma unroll
  for (int g = 0; g < 3; ++g)
    #pragma unroll
    for (int f = 0; f < 4; ++f) {
      float vs = s[g][f], vq = q[g][f];
      vs += __shfl_xor(vs, 16); vs += __shfl_xor(vs, 32);
      vq += __shfl_xor(vq, 16); vq += __shfl_xor(vq, 32);
      s[g][f] = vs; q[g][f] = vq;
    }
  int lane = tid & 63;
  if (lane < 16) {
    int d0 = lane * 4;
    #pragma unroll
    for (int g = 0; g < 3; ++g)
      #pragma unroll
      for (int f = 0; f < 4; ++f) {
        atomicAdd(&acc[2 * g][d0 + f], s[g][f]);
        atomicAdd(&acc[2 * g + 1][d0 + f], q[g][f]);
      }
  }
  __syncthreads();
  for (int v = tid; v < 384; v += 256)
    atomicAdd(&stats[v], acc[v >> 6][v & 63]);
}

// ---------------------------------------------------------------------------
// Kernel B: inline inv_std from stats; build EHL rows [hi(64)|lo(64)] bf16,
// 16B chunks XOR-swizzled by row&7. Also pre-loads out with 8192*EPS_OUT.
// Grid: 2 pairs x 256 row-tiles (32 rows each) = 512 blocks x 256 threads.
__global__ __launch_bounds__(256) void prep_kernel(
    const float* __restrict__ a, const float* __restrict__ p,
    const float* __restrict__ n, const float* __restrict__ stats,
    unsigned short* __restrict__ EHL, float* __restrict__ out) {
  __shared__ float is_s[64];
  int pair = blockIdx.x >> 8;
  int tb   = blockIdx.x & 255;
  int tid  = threadIdx.x;
  if (tid < 32) out[blockIdx.x * 32 + tid] = 8192.0f * EPS_OUT;
  if (tid < 64) {
    float sa = stats[tid], qa = stats[64 + tid];
    float sb = pair ? stats[256 + tid] : stats[128 + tid];
    float qb = pair ? stats[320 + tid] : stats[192 + tid];
    const float invN = 1.0f / (float)NCO;
    float m = (sa + sb) * invN;
    float v = (qa + qb) * invN - m * m;
    is_s[tid] = 1.0f / sqrtf(v);
  }
  __syncthreads();
  const float* bptr = pair ? n : p;
  unsigned short* dst = EHL + (size_t)pair * EHL_PAIR_USHORTS;
  int c0 = tid & 7;          // chunk within row (8 bf16 = 16B)
  int rl = tid >> 3;         // row within block (0..31)
  int row = tb * 32 + rl;
  int d0 = c0 * 8;
  const float* ar = a    + (size_t)row * DFEAT + d0;
  const float* br = bptr + (size_t)row * DFEAT + d0;
  float4 a0 = *(const float4*)(ar);
  float4 a1 = *(const float4*)(ar + 4);
  float4 b0 = *(const float4*)(br);
  float4 b1 = *(const float4*)(br + 4);
  float e[8] = {a0.x - b0.x, a0.y - b0.y, a0.z - b0.z, a0.w - b0.w,
                a1.x - b1.x, a1.y - b1.y, a1.z - b1.z, a1.w - b1.w};
  u16x8 vh, vl;
  #pragma unroll
  for (int j = 0; j < 8; ++j) {
    float ej = e[j] * is_s[d0 + j];
    unsigned short hi = f2bf_rne(ej);
    vh[j] = hi;
    vl[j] = f2bf_rne(ej - bf2f(hi));
  }
  int cs = c0 ^ (row & 7);
  char* drow = (char*)dst + (size_t)row * 256;
  *(u16x8*)(drow + cs * 16)       = vh;   // hi chunk
  *(u16x8*)(drow + (8 + cs) * 16) = vl;   // lo chunk
}

// ---------------------------------------------------------------------------
// Kernel C: symmetric MFMA GEMM. 128x128 tiles, 8 waves (2x4) of 64x32.
// Persistent A-frags in registers; sA buffer reused as second B buffer.
// Grid: 2 pairs x 64 ib x 2 halves = 256 blocks (1/CU), 512 threads.
#define GLOAD(gsrc, ldst)                                                  \
  __builtin_amdgcn_global_load_lds(                                        \
      (const __attribute__((address_space(1))) void*)(gsrc),               \
      (__attribute__((address_space(3))) void*)(ldst), 16, 0, 0)

__global__ __launch_bounds__(512, 2) void mdist_mfma(
    const unsigned short* __restrict__ EHL, float* __restrict__ out) {
  __shared__ __align__(16) unsigned char sX[32768];   // A tile, then B buffer
  __shared__ __align__(16) unsigned char sY[32768];   // B buffer
  int bid  = blockIdx.x;                // pair<<7 | ib<<1 | half
  int pair = bid >> 7;
  int ib   = (bid >> 1) & 63;
  int half = bid & 1;
  const char* base = (const char*)(EHL + (size_t)pair * EHL_PAIR_USHORTS);
  const char* gA = base + (size_t)ib * 32768;
  int tid = threadIdx.x;

  // prologue: A -> sX, B(s=half) -> sY
  {
    int jb0 = (ib + half) & 63;
    const char* gB0 = base + (size_t)jb0 * 32768;
    #pragma unroll
    for (int r = 0; r < 4; ++r) {
      int off = r * 8192 + tid * 16;
      GLOAD(gA + off, sX + off);
      GLOAD(gB0 + off, sY + off);
    }
  }
  __syncthreads();

  int lane = tid & 63, w = tid >> 6;
  int wr = w >> 2, wc = w & 3;          // wave tile: rows wr*64+.., cols wc*32+..
  int l15 = lane & 15, lg = lane >> 4;

  // A fragments, resident for whole kernel: af[hk][m], hk = (half_sel<<1)|ks
  bf16x8 af[4][4];
  #pragma unroll
  for (int hk = 0; hk < 4; ++hk) {
    int c = ((hk >> 1) << 3) | ((hk & 1) << 2) | lg;
    #pragma unroll
    for (int m = 0; m < 4; ++m) {
      int r = wr * 64 + m * 16 + l15;
      int cs = c ^ (r & 7);
      af[hk][m] = *(const bf16x8*)(sX + r * 256 + cs * 16);
    }
  }
  __syncthreads();   // sX now free for B staging

  float rs[4][4];
  #pragma unroll
  for (int m = 0; m < 4; ++m)
    #pragma unroll
    for (int r = 0; r < 4; ++r) rs[m][r] = 0.f;

  const f32x4 zacc = {0.f, 0.f, 0.f, 0.f};
  const int AH[3] = {0, 0, 1};
  const int BH[3] = {0, 1, 0};
  int smax = (ib < 32) ? 32 : 31;
  int cur = 1;                          // sY holds current B

  for (int s = half; s <= smax; s += 2) {
    unsigned char* wbuf = cur ? sX : sY;
    const unsigned char* rbuf = cur ? sY : sX;
    int snext = s + 2;
    if (snext <= smax) {
      int jbn = (ib + snext) & 63;
      const char* gs = base + (size_t)jbn * 32768;
      #pragma unroll
      for (int r = 0; r < 4; ++r) {
        int off = r * 8192 + tid * 16;
        GLOAD(gs + off, wbuf + off);
      }
    }
    // B fragments for this step
    bf16x8 bf[4][2];
    #pragma unroll
    for (int hk = 0; hk < 4; ++hk) {
      int c = ((hk >> 1) << 3) | ((hk & 1) << 2) | lg;
      #pragma unroll
      for (int nn = 0; nn < 2; ++nn) {
        int r = wc * 32 + nn * 16 + l15;
        int cs = c ^ (r & 7);
        bf[hk][nn] = *(const bf16x8*)(rbuf + r * 256 + cs * 16);
      }
    }
    // 48 MFMAs, K=192, fresh accumulator each step
    f32x4 acc[4][2];
    #pragma unroll
    for (int t = 0; t < 3; ++t) {
      #pragma unroll
      for (int ks = 0; ks < 2; ++ks) {
        int ahk = (AH[t] << 1) | ks;
        int bhk = (BH[t] << 1) | ks;
        #pragma unroll
        for (int m = 0; m < 4; ++m) {
          #pragma unroll
          for (int nn = 0; nn < 2; ++nn)
            acc[m][nn] = __builtin_amdgcn_mfma_f32_16x16x32_bf16(
                af[ahk][m], bf[bhk][nn],
                (t == 0 && ks == 0) ? zacc : acc[m][nn], 0, 0, 0);
        }
      }
    }
    // epilogue: f = sqrt(max(q,0)); rows always; cols for off-diag tiles
    if (s == 0) {
      #pragma unroll
      for (int m = 0; m < 4; ++m)
        #pragma unroll
        for (int nn = 0; nn < 2; ++nn)
          #pragma unroll
          for (int r = 0; r < 4; ++r)
            rs[m][r] += __builtin_amdgcn_sqrtf(fmaxf(acc[m][nn][r], 0.f));
    } else {
      float cq0 = 0.f, cq1 = 0.f;
      #pragma unroll
      for (int m = 0; m < 4; ++m)
        #pragma unroll
        for (int nn = 0; nn < 2; ++nn)
          #pragma unroll
          for (int r = 0; r < 4; ++r) {
            float f = __builtin_amdgcn_sqrtf(fmaxf(acc[m][nn][r], 0.f));
            rs[m][r] += f;
            if (nn == 0) cq0 += f; else cq1 += f;
          }
      // reduce col sums over the row-lane groups (lg dimension)
      cq0 += __shfl_xor(cq0, 16); cq0 += __shfl_xor(cq0, 32);
      cq1 += __shfl_xor(cq1, 16); cq1 += __shfl_xor(cq1, 32);
      if (lane < 16) {
        int jb = (ib + s) & 63;
        float* orow = &out[pair * BROWS + jb * 128 + wc * 32 + l15];
        atomicAdd(orow, cq0);
        atomicAdd(orow + 16, cq1);
      }
    }
    __syncthreads();
    cur ^= 1;
  }

  // final row-sum reduce over the 16 col-lanes, one atomic per row per wave
  #pragma unroll
  for (int m = 0; m < 4; ++m)
    #pragma unroll
    for (int r = 0; r < 4; ++r) {
      float v = rs[m][r];
      v += __shfl_xor(v, 1);
      v += __shfl_xor(v, 2);
      v += __shfl_xor(v, 4);
      v += __shfl_xor(v, 8);
      rs[m][r] = v;
    }
  if (l15 == 0) {
    int i0 = ib * 128 + wr * 64;
    #pragma unroll
    for (int m = 0; m < 4; ++m)
      #pragma unroll
      for (int r = 0; r < 4; ++r)
        atomicAdd(&out[pair * BROWS + i0 + m * 16 + lg * 4 + r], rs[m][r]);
  }
}

// ---------------------------------------------------------------------------
extern "C" void kernel_launch(void* const* d_in, const int* in_sizes, int n_in,
                              void* d_out, int out_size, void* d_ws, size_t ws_size,
                              hipStream_t stream) {
  const float* anchor   = (const float*)d_in[0];
  const float* positive = (const float*)d_in[1];
  const float* negative = (const float*)d_in[2];
  float* out = (float*)d_out;
  float* ws  = (float*)d_ws;

  float* stats = ws;
  unsigned short* EHL = (unsigned short*)(ws + WS_EHL_F);

  hipMemsetAsync(stats, 0, 384 * sizeof(float), stream);
  stats_kernel<<<256, 256, 0, stream>>>(anchor, positive, negative, stats);
  prep_kernel<<<512, 256, 0, stream>>>(anchor, positive, negative, stats, EHL, out);
  mdist_mfma<<<256, 512, 0, stream>>>(EHL, out);
}